// Round 7
// baseline (223.773 us; speedup 1.0000x reference)
//
#include <hip/hip_runtime.h>
#include <math.h>

#define N_ROWS 400      // bs*Q
#define M_ROWS 80       // = 5*16
#define K_CLS  134
#define PN     12544    // = 392*32
#define PFULL  65536    // 256*256
#define NSUB   25       // 400/16 n-subtiles
#define TSTEPS 392      // PN/32 MFMA k-steps
#define KSPLIT 196
#define TPB    2        // TSTEPS/KSPLIT

#define ZB_BLOCKS 33    // zeroing blocks in stage1b
#define GY_BLOCKS 245   // 5 j-subtiles * 49 t-chunks

typedef __attribute__((ext_vector_type(4))) float  f32x4;
typedef __attribute__((ext_vector_type(8))) __bf16 bf16x8;

__device__ __forceinline__ float wave_reduce_sum(float v) {
#pragma unroll
    for (int off = 32; off > 0; off >>= 1) v += __shfl_down(v, off, 64);
    return v;
}

// --- block 0: sel = sorted(point_idx) via LDS bit-bitmap + popc scan.
//     blocks 1..25: softmax stats (16 rows each, one per wave). ---
__global__ __launch_bounds__(1024) void sort_softmax_kernel(
        const int* __restrict__ point_idx, int* __restrict__ sel,
        const float* __restrict__ pred_logits,
        float* __restrict__ rowmax, float* __restrict__ rowsum) {
    int tid = threadIdx.x;
    if (blockIdx.x == 0) {
        __shared__ unsigned int bits[PFULL / 32];   // 8 KB
        __shared__ int wtot[16], wbase[16];
        bits[tid] = 0u; bits[tid + 1024] = 0u;
        __syncthreads();
        for (int i = tid; i < PN; i += 1024) {
            int p = point_idx[i];
            atomicOr(&bits[p >> 5], 1u << (p & 31));
        }
        __syncthreads();
        unsigned int w0 = bits[tid * 2], w1 = bits[tid * 2 + 1];
        int cnt = __popc(w0) + __popc(w1);
        int lane = tid & 63, wid = tid >> 6;
        int v = cnt;
#pragma unroll
        for (int off = 1; off < 64; off <<= 1) {
            int u = __shfl_up(v, off, 64);
            if (lane >= off) v += u;
        }
        if (lane == 63) wtot[wid] = v;
        __syncthreads();
        if (tid == 0) {
            int run = 0;
#pragma unroll
            for (int i = 0; i < 16; ++i) { wbase[i] = run; run += wtot[i]; }
        }
        __syncthreads();
        int base = wbase[wid] + (v - cnt);          // exclusive prefix
        int p0 = tid * 64;
        while (w0) { int b = __builtin_ctz(w0); w0 &= w0 - 1; sel[base++] = p0 + b; }
        p0 += 32;
        while (w1) { int b = __builtin_ctz(w1); w1 &= w1 - 1; sel[base++] = p0 + b; }
    } else {
        // softmax stats: one row per wave, 16 waves/block
        int wave = tid >> 6, lane = tid & 63;
        int n = (blockIdx.x - 1) * 16 + wave;       // < 400
        const float* row = pred_logits + n * K_CLS;
        float mx = -1e30f;
        for (int k = lane; k < K_CLS; k += 64) mx = fmaxf(mx, row[k]);
#pragma unroll
        for (int off = 32; off > 0; off >>= 1) mx = fmaxf(mx, __shfl_down(mx, off, 64));
        mx = __shfl(mx, 0, 64);
        float se = 0.f;
        for (int k = lane; k < K_CLS; k += 64) se += expf(row[k] - mx);
        se = wave_reduce_sum(se);
        if (lane == 0) { rowmax[n] = mx; rowsum[n] = se; }
    }
}

// --- stage1b: blocks [0,ZB) zero the accumulator region (float4 stores);
//     blocks [ZB, ZB+245) gather y into B-fragment layout + ypart sums. ---
__global__ __launch_bounds__(512) void stage1b_kernel(
        const float* __restrict__ tgt_masks, const int* __restrict__ sel,
        __bf16* __restrict__ Yb, float* __restrict__ ypart,
        float* __restrict__ zero_region, int zero_n4) {
    __shared__ float smem[128];
    int b = blockIdx.x;
    if (b < ZB_BLOCKS) {
        int i = b * 512 + threadIdx.x;              // float4 index
        if (i < zero_n4) {
            f32x4 z = {0.f, 0.f, 0.f, 0.f};
            ((f32x4*)zero_region)[i] = z;
        }
        return;
    }
    // gather y: frag (t,j), lane l holds B[k=t*32+(l>>4)*8+jj][m=16*j+(l&15)]
    int bb = b - ZB_BLOCKS;
    int j = bb / 49, tch = bb % 49;
    int wave = threadIdx.x >> 6, lane = threadIdx.x & 63;
    int colL = lane & 15, quad = lane >> 4;
    int m = 16 * j + colL;
    int t = tch * 8 + wave;
    int k0 = t * 32 + quad * 8;
    const float* yrow = tgt_masks + (size_t)m * PFULL;
    int idx[8];
    *(int4*)(idx)     = *(const int4*)(sel + k0);
    *(int4*)(idx + 4) = *(const int4*)(sel + k0 + 4);
    bf16x8 v; float acc = 0.f;
#pragma unroll
    for (int jj = 0; jj < 8; ++jj) {
        float y = yrow[idx[jj]];
        v[jj] = (__bf16)y;
        acc += y;
    }
    ((bf16x8*)Yb)[(size_t)(t * 5 + j) * 64 + lane] = v;
    acc += __shfl_down(acc, 32, 64);
    acc += __shfl_down(acc, 16, 64);
    if (quad == 0) smem[wave * 16 + colL] = acc;
    __syncthreads();
    if (threadIdx.x < 16) {
        float s = 0.f;
#pragma unroll
        for (int wv = 0; wv < 8; ++wv) s += smem[wv * 16 + threadIdx.x];
        ypart[tch * M_ROWS + 16 * j + threadIdx.x] = s;   // non-atomic, block-owned
    }
}

// --- fused gather+GEMM: one wave per (nsub, kchunk), TPB=2 t-steps,
//     all loads issued before first MFMA. Sorted sel -> line locality. ---
__global__ __launch_bounds__(256) void gemm_fused_kernel(
        const float* __restrict__ pred_masks, const int* __restrict__ sel,
        const __bf16* __restrict__ Yb,
        float* __restrict__ xyacc, float* __restrict__ syacc,
        float* __restrict__ spsum, float* __restrict__ ssum) {
    int wave = threadIdx.x >> 6, lane = threadIdx.x & 63;
    int flat = blockIdx.x * 4 + wave;               // exactly NSUB*KSPLIT waves
    int nsub = flat / KSPLIT, kc = flat % KSPLIT;
    int n0 = nsub * 16;
    int colL = lane & 15, quad = lane >> 4;
    int tbase = kc * TPB;

    const float* row = pred_masks + (size_t)(n0 + colL) * PFULL;
    const bf16x8* Yfrag = (const bf16x8*)Yb;

    f32x4 accX[5], accS[5];
    f32x4 zero = {0.f, 0.f, 0.f, 0.f};
#pragma unroll
    for (int j = 0; j < 5; ++j) { accX[j] = zero; accS[j] = zero; }
    float sumS = 0.f, sumSP = 0.f;

    float xs[TPB][8];
    bf16x8 Bbuf[TPB][5];
    // issue ALL loads up-front (26 outstanding VMEM)
#pragma unroll
    for (int i = 0; i < TPB; ++i) {
        int t = tbase + i;
        int k0 = t * 32 + quad * 8;
        int idx[8];
        *(int4*)(idx)     = *(const int4*)(sel + k0);
        *(int4*)(idx + 4) = *(const int4*)(sel + k0 + 4);
#pragma unroll
        for (int jj = 0; jj < 8; ++jj) xs[i][jj] = row[idx[jj]];
        const bf16x8* q = Yfrag + (size_t)(t * 5) * 64 + lane;
#pragma unroll
        for (int j = 0; j < 5; ++j) Bbuf[i][j] = q[(size_t)j * 64];
    }
#pragma unroll
    for (int i = 0; i < TPB; ++i) {
        bf16x8 aX, aS;
#pragma unroll
        for (int jj = 0; jj < 8; ++jj) {
            float x  = xs[i][jj];
            float ax = fabsf(x);
            float e  = __expf(-ax);
            float inv = __builtin_amdgcn_rcpf(1.f + e);
            float sig = (x >= 0.f) ? inv : e * inv;
            float sp  = fmaxf(x, 0.f) + __logf(1.f + e);
            aX[jj] = (__bf16)x; aS[jj] = (__bf16)sig;
            sumS += sig; sumSP += sp;
        }
#pragma unroll
        for (int j = 0; j < 5; ++j) {
            accX[j] = __builtin_amdgcn_mfma_f32_16x16x32_bf16(aX, Bbuf[i][j], accX[j], 0, 0, 0);
            accS[j] = __builtin_amdgcn_mfma_f32_16x16x32_bf16(aS, Bbuf[i][j], accS[j], 0, 0, 0);
        }
    }

    // C/D: n = n0 + quad*4 + reg, m = 16*j + colL  [verified layout]
#pragma unroll
    for (int j = 0; j < 5; ++j)
#pragma unroll
        for (int r = 0; r < 4; ++r) {
            int n = n0 + quad * 4 + r;
            int m = 16 * j + colL;
            atomicAdd(&xyacc[n * M_ROWS + m], accX[j][r]);
            atomicAdd(&syacc[n * M_ROWS + m], accS[j][r]);
        }
    sumS  += __shfl_down(sumS, 32, 64);
    sumS  += __shfl_down(sumS, 16, 64);
    sumSP += __shfl_down(sumSP, 32, 64);
    sumSP += __shfl_down(sumSP, 16, 64);
    if (lane < 16) {
        atomicAdd(&ssum[n0 + lane], sumS);
        atomicAdd(&spsum[n0 + lane], sumSP);
    }
}

// --- combine all cost terms (reduces ypart -> ysum inline) ---
__global__ void combine_kernel(const float* __restrict__ logits,
                               const int* __restrict__ tgt_labels,
                               const float* __restrict__ rowmax,
                               const float* __restrict__ rowsum,
                               const float* __restrict__ spsum,
                               const float* __restrict__ ssum,
                               const float* __restrict__ ypart,
                               const float* __restrict__ xyacc,
                               const float* __restrict__ syacc,
                               float* __restrict__ out) {
    int idx = blockIdx.x * blockDim.x + threadIdx.x;
    if (idx >= N_ROWS * M_ROWS) return;
    int n = idx / M_ROWS, m = idx % M_ROWS;
    float ysum = 0.f;
#pragma unroll
    for (int t = 0; t < 49; ++t) ysum += ypart[t * M_ROWS + m];
    int tid = tgt_labels[m];
    tid = min(max(tid, 0), K_CLS - 1);
    float p = expf(logits[n * K_CLS + tid] - rowmax[n]) / rowsum[n];
    float cost_class = -p;
    float cost_mask = (spsum[n] - xyacc[idx]) * (1.0f / PN);
    float cost_dice = 1.f - (2.f * syacc[idx] + 1.f) / (ssum[n] + ysum + 1.f);
    out[idx] = 2.f * cost_class + 5.f * cost_mask + 5.f * cost_dice;
}

extern "C" void kernel_launch(void* const* d_in, const int* in_sizes, int n_in,
                              void* d_out, int out_size, void* d_ws, size_t ws_size,
                              hipStream_t stream) {
    const float* pred_logits = (const float*)d_in[0];   // (4,100,134)
    const float* pred_masks  = (const float*)d_in[1];   // (4,100,256,256)
    const int*   tgt_labels  = (const int*)d_in[2];     // (80,)
    const float* tgt_masks   = (const float*)d_in[3];   // (80,256,256)
    const int*   point_idx   = (const int*)d_in[4];     // (12544,)
    float* out = (float*)d_out;                         // (4,100,80)

    char* ws = (char*)d_ws;
    size_t off = 0;
    auto carve = [&](size_t nbytes) {
        char* p = ws + off;
        off += (nbytes + 255) & ~(size_t)255;
        return p;
    };
    // ---- zeroed-by-stage1b region (contiguous) ----
    float* xyacc = (float*)carve((size_t)N_ROWS * M_ROWS * 4);
    float* syacc = (float*)carve((size_t)N_ROWS * M_ROWS * 4);
    float* spsum = (float*)carve(N_ROWS * 4);
    float* ssum  = (float*)carve(N_ROWS * 4);
    int zero_n4 = (int)(off / 16);                      // float4 count (256-aligned)
    // ---- fully-overwritten region ----
    int*   sel    = (int*)carve(PN * 4);
    float* rowmax = (float*)carve(N_ROWS * 4);
    float* rowsum = (float*)carve(N_ROWS * 4);
    float* ypart  = (float*)carve(49 * M_ROWS * 4);
    __bf16* Yb = (__bf16*)carve((size_t)TSTEPS * 5 * 1024); // 2.01 MB
    (void)ws_size; (void)in_sizes; (void)n_in; (void)out_size;

    sort_softmax_kernel<<<26, 1024, 0, stream>>>(point_idx, sel, pred_logits, rowmax, rowsum);
    stage1b_kernel<<<ZB_BLOCKS + GY_BLOCKS, 512, 0, stream>>>(
        tgt_masks, sel, Yb, ypart, xyacc, zero_n4);
    gemm_fused_kernel<<<NSUB * KSPLIT / 4, 256, 0, stream>>>(
        pred_masks, sel, Yb, xyacc, syacc, spsum, ssum);
    combine_kernel<<<(N_ROWS * M_ROWS + 255) / 256, 256, 0, stream>>>(
        pred_logits, tgt_labels, rowmax, rowsum, spsum, ssum, ypart, xyacc, syacc, out);
}

// Round 8
// 217.108 us; speedup vs baseline: 1.0307x; 1.0307x over previous
//
#include <hip/hip_runtime.h>
#include <math.h>

#define N_ROWS 400      // bs*Q
#define M_ROWS 80       // = 5*16
#define K_CLS  134
#define PN     12544    // = 392*32
#define PFULL  65536    // 256*256
#define NSUB   25       // 400/16 n-subtiles
#define TSTEPS 392      // PN/32 MFMA k-steps
#define KSPLIT 196      // kc chunks (TPB=2 t-steps each)
#define TPB    2
#define KCG    49       // kc groups (4 kc = 1 block)

#define GY_BLOCKS 245   // 5 j-subtiles * 49 t-chunks

typedef __attribute__((ext_vector_type(4))) float  f32x4;
typedef __attribute__((ext_vector_type(8))) __bf16 bf16x8;

__device__ __forceinline__ float wave_reduce_sum(float v) {
#pragma unroll
    for (int off = 32; off > 0; off >>= 1) v += __shfl_down(v, off, 64);
    return v;
}

// --- block 0: sel = sorted(point_idx) via LDS bit-bitmap + popc scan.
//     blocks 1..25: softmax stats (16 rows each, one per wave). ---
__global__ __launch_bounds__(1024) void sort_softmax_kernel(
        const int* __restrict__ point_idx, int* __restrict__ sel,
        const float* __restrict__ pred_logits,
        float* __restrict__ rowmax, float* __restrict__ rowsum) {
    int tid = threadIdx.x;
    if (blockIdx.x == 0) {
        __shared__ unsigned int bits[PFULL / 32];   // 8 KB
        __shared__ int wtot[16], wbase[16];
        bits[tid] = 0u; bits[tid + 1024] = 0u;
        __syncthreads();
        for (int i = tid; i < PN; i += 1024) {
            int p = point_idx[i];
            atomicOr(&bits[p >> 5], 1u << (p & 31));
        }
        __syncthreads();
        unsigned int w0 = bits[tid * 2], w1 = bits[tid * 2 + 1];
        int cnt = __popc(w0) + __popc(w1);
        int lane = tid & 63, wid = tid >> 6;
        int v = cnt;
#pragma unroll
        for (int off = 1; off < 64; off <<= 1) {
            int u = __shfl_up(v, off, 64);
            if (lane >= off) v += u;
        }
        if (lane == 63) wtot[wid] = v;
        __syncthreads();
        if (tid == 0) {
            int run = 0;
#pragma unroll
            for (int i = 0; i < 16; ++i) { wbase[i] = run; run += wtot[i]; }
        }
        __syncthreads();
        int base = wbase[wid] + (v - cnt);          // exclusive prefix
        int p0 = tid * 64;
        while (w0) { int b = __builtin_ctz(w0); w0 &= w0 - 1; sel[base++] = p0 + b; }
        p0 += 32;
        while (w1) { int b = __builtin_ctz(w1); w1 &= w1 - 1; sel[base++] = p0 + b; }
    } else {
        // softmax stats: one row per wave, 16 waves/block
        int wave = tid >> 6, lane = tid & 63;
        int n = (blockIdx.x - 1) * 16 + wave;       // < 400
        const float* row = pred_logits + n * K_CLS;
        float mx = -1e30f;
        for (int k = lane; k < K_CLS; k += 64) mx = fmaxf(mx, row[k]);
#pragma unroll
        for (int off = 32; off > 0; off >>= 1) mx = fmaxf(mx, __shfl_down(mx, off, 64));
        mx = __shfl(mx, 0, 64);
        float se = 0.f;
        for (int k = lane; k < K_CLS; k += 64) se += expf(row[k] - mx);
        se = wave_reduce_sum(se);
        if (lane == 0) { rowmax[n] = mx; rowsum[n] = se; }
    }
}

// --- gather y into B-fragment layout + per-chunk ysum partials ---
__global__ __launch_bounds__(512) void gather_y_kernel(
        const float* __restrict__ tgt_masks, const int* __restrict__ sel,
        __bf16* __restrict__ Yb, float* __restrict__ ypart) {
    __shared__ float smem[128];
    int b = blockIdx.x;
    // frag (t,j): lane l holds B[k=t*32+(l>>4)*8+jj][m=16*j+(l&15)]
    int j = b / 49, tch = b % 49;
    int wave = threadIdx.x >> 6, lane = threadIdx.x & 63;
    int colL = lane & 15, quad = lane >> 4;
    int m = 16 * j + colL;
    int t = tch * 8 + wave;
    int k0 = t * 32 + quad * 8;
    const float* yrow = tgt_masks + (size_t)m * PFULL;
    int idx[8];
    *(int4*)(idx)     = *(const int4*)(sel + k0);
    *(int4*)(idx + 4) = *(const int4*)(sel + k0 + 4);
    bf16x8 v; float acc = 0.f;
#pragma unroll
    for (int jj = 0; jj < 8; ++jj) {
        float y = yrow[idx[jj]];
        v[jj] = (__bf16)y;
        acc += y;
    }
    ((bf16x8*)Yb)[(size_t)(t * 5 + j) * 64 + lane] = v;
    acc += __shfl_down(acc, 32, 64);
    acc += __shfl_down(acc, 16, 64);
    if (quad == 0) smem[wave * 16 + colL] = acc;
    __syncthreads();
    if (threadIdx.x < 16) {
        float s = 0.f;
#pragma unroll
        for (int wv = 0; wv < 8; ++wv) s += smem[wv * 16 + threadIdx.x];
        ypart[tch * M_ROWS + 16 * j + threadIdx.x] = s;   // non-atomic, block-owned
    }
}

// --- fused gather+GEMM, ZERO global atomics.
//     Block = 4 waves, one nsub, kc = kcg*4+wave (consecutive sorted ranges).
//     Epilogue: 4-wave LDS reduce, then non-atomic partial writes per kcg. ---
__global__ __launch_bounds__(256) void gemm_fused_kernel(
        const float* __restrict__ pred_masks, const int* __restrict__ sel,
        const __bf16* __restrict__ Yb,
        float* __restrict__ xypart, float* __restrict__ sypart,
        float* __restrict__ rowS, float* __restrict__ rowSP) {
    __shared__ float red[4][40][64];       // 40 KB, lane-major: conflict-free
    __shared__ float rowred[4][2][16];
    int wave = threadIdx.x >> 6, lane = threadIdx.x & 63;
    int nsub = blockIdx.x / KCG, kcg = blockIdx.x % KCG;
    int kc = kcg * 4 + wave;
    int n0 = nsub * 16;
    int colL = lane & 15, quad = lane >> 4;
    int tbase = kc * TPB;

    const float* row = pred_masks + (size_t)(n0 + colL) * PFULL;
    const bf16x8* Yfrag = (const bf16x8*)Yb;

    f32x4 accX[5], accS[5];
    f32x4 zero = {0.f, 0.f, 0.f, 0.f};
#pragma unroll
    for (int j = 0; j < 5; ++j) { accX[j] = zero; accS[j] = zero; }
    float sumS = 0.f, sumSP = 0.f;

    float xs[TPB][8];
    bf16x8 Bbuf[TPB][5];
    // issue ALL loads up-front (26 outstanding VMEM)
#pragma unroll
    for (int i = 0; i < TPB; ++i) {
        int t = tbase + i;
        int k0 = t * 32 + quad * 8;
        int idx[8];
        *(int4*)(idx)     = *(const int4*)(sel + k0);
        *(int4*)(idx + 4) = *(const int4*)(sel + k0 + 4);
#pragma unroll
        for (int jj = 0; jj < 8; ++jj) xs[i][jj] = row[idx[jj]];
        const bf16x8* q = Yfrag + (size_t)(t * 5) * 64 + lane;
#pragma unroll
        for (int j = 0; j < 5; ++j) Bbuf[i][j] = q[(size_t)j * 64];
    }
#pragma unroll
    for (int i = 0; i < TPB; ++i) {
        bf16x8 aX, aS;
#pragma unroll
        for (int jj = 0; jj < 8; ++jj) {
            float x  = xs[i][jj];
            float ax = fabsf(x);
            float e  = __expf(-ax);
            float inv = __builtin_amdgcn_rcpf(1.f + e);
            float sig = (x >= 0.f) ? inv : e * inv;
            float sp  = fmaxf(x, 0.f) + __logf(1.f + e);
            aX[jj] = (__bf16)x; aS[jj] = (__bf16)sig;
            sumS += sig; sumSP += sp;
        }
#pragma unroll
        for (int j = 0; j < 5; ++j) {
            accX[j] = __builtin_amdgcn_mfma_f32_16x16x32_bf16(aX, Bbuf[i][j], accX[j], 0, 0, 0);
            accS[j] = __builtin_amdgcn_mfma_f32_16x16x32_bf16(aS, Bbuf[i][j], accS[j], 0, 0, 0);
        }
    }

    // ---- stash accumulators in LDS ----
#pragma unroll
    for (int j = 0; j < 5; ++j)
#pragma unroll
        for (int r = 0; r < 4; ++r) {
            red[wave][j * 4 + r][lane]      = accX[j][r];
            red[wave][20 + j * 4 + r][lane] = accS[j][r];
        }
    sumS  += __shfl_down(sumS, 32, 64);
    sumS  += __shfl_down(sumS, 16, 64);
    sumSP += __shfl_down(sumSP, 32, 64);
    sumSP += __shfl_down(sumSP, 16, 64);
    if (lane < 16) { rowred[wave][0][lane] = sumS; rowred[wave][1][lane] = sumSP; }
    __syncthreads();
    // ---- each wave reduces a 10-value slice across the 4 waves, writes partials ----
#pragma unroll
    for (int v0 = 0; v0 < 10; ++v0) {
        int v = wave * 10 + v0;
        float s = red[0][v][lane] + red[1][v][lane] + red[2][v][lane] + red[3][v][lane];
        int vv = (v < 20) ? v : v - 20;
        int j = vv >> 2, r = vv & 3;
        int n = n0 + quad * 4 + r, m = 16 * j + colL;   // verified C/D layout
        float* dst = (v < 20) ? xypart : sypart;
        dst[(size_t)kcg * (N_ROWS * M_ROWS) + n * M_ROWS + m] = s;
    }
    if (threadIdx.x < 16) {
        rowS[kcg * N_ROWS + n0 + threadIdx.x] =
            rowred[0][0][threadIdx.x] + rowred[1][0][threadIdx.x] +
            rowred[2][0][threadIdx.x] + rowred[3][0][threadIdx.x];
    } else if (threadIdx.x < 32) {
        int l = threadIdx.x - 16;
        rowSP[kcg * N_ROWS + n0 + l] =
            rowred[0][1][l] + rowred[1][1][l] + rowred[2][1][l] + rowred[3][1][l];
    }
}

// --- combine: reduce partials (49 groups) + all cost terms ---
__global__ void combine_kernel(const float* __restrict__ logits,
                               const int* __restrict__ tgt_labels,
                               const float* __restrict__ rowmax,
                               const float* __restrict__ rowsum,
                               const float* __restrict__ rowS,
                               const float* __restrict__ rowSP,
                               const float* __restrict__ ypart,
                               const float* __restrict__ xypart,
                               const float* __restrict__ sypart,
                               float* __restrict__ out) {
    int idx = blockIdx.x * blockDim.x + threadIdx.x;
    if (idx >= N_ROWS * M_ROWS) return;
    int n = idx / M_ROWS, m = idx % M_ROWS;
    float xy = 0.f, sy = 0.f, ssumv = 0.f, spsumv = 0.f, ysum = 0.f;
#pragma unroll 7
    for (int g = 0; g < KCG; ++g) {
        xy += xypart[(size_t)g * (N_ROWS * M_ROWS) + idx];
        sy += sypart[(size_t)g * (N_ROWS * M_ROWS) + idx];
        ssumv  += rowS[g * N_ROWS + n];
        spsumv += rowSP[g * N_ROWS + n];
        ysum += ypart[g * M_ROWS + m];
    }
    int tid = tgt_labels[m];
    tid = min(max(tid, 0), K_CLS - 1);
    float p = expf(logits[n * K_CLS + tid] - rowmax[n]) / rowsum[n];
    float cost_class = -p;
    float cost_mask = (spsumv - xy) * (1.0f / PN);
    float cost_dice = 1.f - (2.f * sy + 1.f) / (ssumv + ysum + 1.f);
    out[idx] = 2.f * cost_class + 5.f * cost_mask + 5.f * cost_dice;
}

extern "C" void kernel_launch(void* const* d_in, const int* in_sizes, int n_in,
                              void* d_out, int out_size, void* d_ws, size_t ws_size,
                              hipStream_t stream) {
    const float* pred_logits = (const float*)d_in[0];   // (4,100,134)
    const float* pred_masks  = (const float*)d_in[1];   // (4,100,256,256)
    const int*   tgt_labels  = (const int*)d_in[2];     // (80,)
    const float* tgt_masks   = (const float*)d_in[3];   // (80,256,256)
    const int*   point_idx   = (const int*)d_in[4];     // (12544,)
    float* out = (float*)d_out;                         // (4,100,80)

    char* ws = (char*)d_ws;
    size_t off = 0;
    auto carve = [&](size_t nbytes) {
        char* p = ws + off;
        off += (nbytes + 255) & ~(size_t)255;
        return p;
    };
    // all buffers fully overwritten every launch -> NO zero-init anywhere
    int*   sel    = (int*)carve(PN * 4);
    float* rowmax = (float*)carve(N_ROWS * 4);
    float* rowsum = (float*)carve(N_ROWS * 4);
    float* ypart  = (float*)carve(KCG * M_ROWS * 4);
    float* rowS   = (float*)carve(KCG * N_ROWS * 4);
    float* rowSP  = (float*)carve(KCG * N_ROWS * 4);
    float* xypart = (float*)carve((size_t)KCG * N_ROWS * M_ROWS * 4);  // 6.27 MB
    float* sypart = (float*)carve((size_t)KCG * N_ROWS * M_ROWS * 4);  // 6.27 MB
    __bf16* Yb = (__bf16*)carve((size_t)TSTEPS * 5 * 1024);            // 2.01 MB
    (void)ws_size; (void)in_sizes; (void)n_in; (void)out_size;

    sort_softmax_kernel<<<26, 1024, 0, stream>>>(point_idx, sel, pred_logits, rowmax, rowsum);
    gather_y_kernel<<<GY_BLOCKS, 512, 0, stream>>>(tgt_masks, sel, Yb, ypart);
    gemm_fused_kernel<<<NSUB * KCG, 256, 0, stream>>>(
        pred_masks, sel, Yb, xypart, sypart, rowS, rowSP);
    combine_kernel<<<(N_ROWS * M_ROWS + 255) / 256, 256, 0, stream>>>(
        pred_logits, tgt_labels, rowmax, rowsum, rowS, rowSP, ypart, xypart, sypart, out);
}